// Round 3
// baseline (1875.567 us; speedup 1.0000x reference)
//
#include <hip/hip_runtime.h>

#define NTGT 2048
#define NSRC 4096
#define NPATCH 32
#define PITCH 516          // 512 cols + 4 pad (divisible by 4 -> float4 aligned)
#define NCGP 3269          // repacked CG table size
#define NSEG 22

// segment schedule: SEGMAP[idx] = canonical seg (pair*2 + half); pairs 0..8 = (j-1)*3+(l-1), 9=copyA, 10=copyB
__constant__ int SEGMAP[NSEG] = {16,17,10,11,14,15,8,9, 0,1,2,3,6,7,4,5, 12,13,18,19,20,21};
__constant__ int CGB_[9] = {0,81,306,558,783,1183,1708,1960,2485};

// ---------------- CG math (device, double precision) ----------------
__device__ double factd(int n) { double r = 1.0; for (int i = 2; i <= n; ++i) r *= i; return r; }

__device__ double su2_cg(int j1, int m1, int j2, int m2, int j3, int m3) {
  if (m3 != m1 + m2) return 0.0;
  int vmin = max(max(-j1 + j2 + m3, -j1 + m1), 0);
  int vmax = min(min(j2 + j3 + m1, j3 - j1 + j2), j3 + m3);
  double cc = sqrt((2.0*j3 + 1.0) * factd(j3 + j1 - j2) * factd(j3 - j1 + j2) * factd(j1 + j2 - j3)
                   / factd(j1 + j2 + j3 + 1)
                   * factd(j3 + m3) * factd(j3 - m3)
                   / (factd(j1 - m1) * factd(j1 + m1) * factd(j2 - m2) * factd(j2 + m2)));
  double s = 0.0;
  for (int v = vmin; v <= vmax; ++v) {
    double sgn = ((v + j2 + m2) & 1) ? -1.0 : 1.0;
    s += sgn * factd(j2 + j3 + m1 - v) * factd(j1 - m1 + v)
         / (factd(v) * factd(j3 - j1 + j2 - v) * factd(j3 + m3 - v) * factd(v + j1 - j2 - m3));
  }
  return cc * s;
}

struct C2 { double re, im; };

__device__ C2 qent(int l, int r, int c) {
  double re = 0.0, im = 0.0;
  const double is2 = 0.70710678118654752440;
  int m = r - l;
  if (m < 0) {
    if (c == l - m) re = is2;
    else if (c == l + m) im = -is2;
  } else if (m == 0) {
    if (c == l) re = 1.0;
  } else {
    double sgn = (m & 1) ? -1.0 : 1.0;
    if (c == l + m) re = sgn * is2;
    else if (c == l - m) im = sgn * is2;
  }
  const double pr[4] = {1.0, 0.0, -1.0, 0.0};
  const double pi[4] = {0.0, -1.0, 0.0, 1.0};
  double a = pr[l & 3], bb = pi[l & 3];
  C2 o; o.re = re * a - im * bb; o.im = re * bb + im * a; return o;
}

// Repacked layout: cg[CGB_[pair] + z_glob*(nj*nl) + mj*nl + ml], z_glob over J ascending.
__global__ void cg_init_kernel(float* __restrict__ cg) {
  const int p = blockIdx.x;
  const int j = p / 3 + 1, l = p % 3 + 1;
  const int Jmin = abs(j - l), Jmax = min(j + l, 3);
  const int nj = 2*j + 1, nl = 2*l + 1, njnl = nj * nl;
  __shared__ double tab[4][49];
  for (int q = threadIdx.x; q < (Jmax - Jmin + 1) * njnl; q += blockDim.x) {
    int Ji = q / njnl, ik = q % njnl;
    int J = Jmin + Ji;
    int i = ik / nl, k = ik % nl;
    int m = (i - j) + (k - l) + J;
    tab[Ji][ik] = (m >= 0 && m <= 2*J) ? su2_cg(j, i - j, l, k - l, J, m - J) : 0.0;
  }
  __syncthreads();
  const int R = (Jmax + 1) * (Jmax + 1) - Jmin * Jmin;
  const int base = CGB_[p];
  for (int e = threadIdx.x; e < R * njnl; e += blockDim.x) {
    int z = e / njnl, r = e % njnl;
    int mj = r / nl, ml = r % nl;
    int J = Jmin, zw = z;
    while (zw >= 2*J + 1) { zw -= 2*J + 1; ++J; }
    double acc = 0.0;
    for (int i = 0; i < nj; ++i)
      for (int k = 0; k < nl; ++k) {
        int m = (i - j) + (k - l) + J;
        if (m < 0 || m > 2*J) continue;
        double s2 = tab[J - Jmin][i * nl + k];
        if (s2 == 0.0) continue;
        C2 qa = qent(j, i, mj), qb = qent(l, k, ml), qc = qent(J, m, zw);
        double r1 = qa.re * qb.re - qa.im * qb.im;
        double i1 = qa.re * qb.im + qa.im * qb.re;
        acc += (r1 * qc.re + i1 * qc.im) * s2;
      }
    cg[base + e] = (float)acc;
  }
}

// ---------------- compile-time tables ----------------
__device__ constexpr int OBc(int J)  { return J==0 ? 0 : J==1 ? 1572864 : J==2 ? 12189696 : 33816576; }
__device__ constexpr int WWc(int J)  { return J==0 ? 384 : J==1 ? 864 : J==2 ? 1056 : 960; }
__device__ constexpr int NJWc(int J) { return (2*J+1) * WWc(J); }
__device__ constexpr int COLc(int j, int l, int J) {
  return (j==1&&l==1) ? (J==0?1:2)
       : (j==1&&l==2) ? (J==1?4:J==2?5:4)
       : (j==1&&l==3) ? (J==2?8:7)
       : (j==2&&l==1) ? (J==1?3:J==2?3:2)
       : (j==2&&l==2) ? (J==0?2:J==1?5:J==2?6:5)
       : (j==2&&l==3) ? (J==1?7:J==2?9:8)
       : (j==3&&l==1) ? (J==2?4:3)
       : (j==3&&l==2) ? (J==1?6:J==2?7:6)
       :                (J==0?3:J==1?8:J==2?10:9);
}
__device__ constexpr int CGBc(int j, int l) {
  return (j==1&&l==1)?0 : (j==1&&l==2)?81 : (j==1&&l==3)?306
       : (j==2&&l==1)?558 : (j==2&&l==2)?783 : (j==2&&l==3)?1183
       : (j==3&&l==1)?1708 : (j==3&&l==2)?1960 : 2485;
}

// ---------------- phase-2 bodies ----------------
template<int JT, int LT>
__device__ __forceinline__ void pair_body(const float* __restrict__ y_lds,
                                          const float* __restrict__ cg_lds,
                                          float* __restrict__ out,
                                          int z, int ch4, int s, int bv) {
  constexpr int nj = 2*JT + 1, nl = 2*LT + 1, njnl = nj * nl;
  constexpr int Jmin = (JT > LT) ? (JT - LT) : (LT - JT);
  constexpr int Jmax = (JT + LT < 3) ? (JT + LT) : 3;
  constexpr int R = (Jmax + 1) * (Jmax + 1) - Jmin * Jmin;
  if (z >= R) return;
  const float* cgp = cg_lds + CGBc(JT, LT) + z * njnl;
  const float* yb  = y_lds + ch4 * 4;
  float a0 = 0.f, a1 = 0.f, a2 = 0.f, a3 = 0.f;
  #pragma unroll
  for (int e = 0; e < njnl; ++e) {
    const int mj = e / nl, ml = e % nl;   // compile-time
    const float4 yq = *(const float4*)(yb + (JT*JT + mj) * PITCH + LT*LT*32 + ml*32);
    const float c = cgp[e];
    a0 = fmaf(c, yq.x, a0); a1 = fmaf(c, yq.y, a1);
    a2 = fmaf(c, yq.z, a2); a3 = fmaf(c, yq.w, a3);
  }
  int zz = z;
  #pragma unroll
  for (int J = Jmin; J <= Jmax; ++J) {
    if (zz < 2*J + 1) {
      const size_t addr = (size_t)OBc(J) + (size_t)bv * NJWc(J) + (size_t)zz * WWc(J)
                        + COLc(JT, LT, J) * 96 + s * 32 + ch4 * 4;
      float4 o; o.x = a0; o.y = a1; o.z = a2; o.w = a3;
      *(float4*)&out[addr] = o;
      return;
    }
    zz -= 2*J + 1;
  }
}

__device__ __forceinline__ void copyA(const float* __restrict__ y_lds, float* __restrict__ out,
                                      int z, int ch4, int s, int bv) {
  // out[j][col 0] <- y[sh = j^2 + mj][l=0 cols]; z = sh (0..15)
  const float4 yq = *(const float4*)&y_lds[z * PITCH + ch4 * 4];
  #pragma unroll
  for (int j = 0; j < 4; ++j) {
    if (z >= j*j && z < (j+1)*(j+1)) {
      const size_t addr = (size_t)OBc(j) + (size_t)bv * NJWc(j) + (size_t)(z - j*j) * WWc(j)
                        + s * 32 + ch4 * 4;
      *(float4*)&out[addr] = yq;
    }
  }
}

__device__ __forceinline__ void copyB(const float* __restrict__ y_lds, float* __restrict__ out,
                                      int z, int ch4, int s, int bv) {
  // out[l][col 1] <- y[sh=0][l-block col ml]; z = 0..14 -> (l, ml)
  if (z >= 15) return;
  #pragma unroll
  for (int l = 1; l <= 3; ++l) {
    if (z >= l*l - 1 && z < l*l + 2*l) {
      const int ml = z - (l*l - 1);
      const float4 yq = *(const float4*)&y_lds[l*l*32 + ml*32 + ch4*4];
      const size_t addr = (size_t)OBc(l) + (size_t)bv * NJWc(l) + (size_t)ml * WWc(l)
                        + 96 + s * 32 + ch4 * 4;
      *(float4*)&out[addr] = yq;
    }
  }
}

// ---------------- main fused kernel: one block per (bv, shell s) ----------------
__global__ __launch_bounds__(512, 6) void sh_conv_kernel(
    const float* __restrict__ f0, const float* __restrict__ f1,
    const float* __restrict__ f2, const float* __restrict__ f3,
    const float* __restrict__ kern, const int* __restrict__ pidx,
    const float* __restrict__ cg, float* __restrict__ out) {
  __shared__ float y_lds[16 * PITCH];   // 33.0 KB
  __shared__ float cg_lds[NCGP];        // 13.1 KB
  const int tid = threadIdx.x;
  // XCD-cohort mapping: all 3 shell-blocks of one bv on the same XCD, temporally adjacent
  const int xcd  = blockIdx.x & 7;
  const int slot = blockIdx.x >> 3;     // 0..1535
  const int s    = slot % 3;
  const int bv   = (xcd << 9) | (slot / 3);   // 0..4095
  const int b    = bv >> 11;

  for (int i = tid; i < NCGP; i += 512) cg_lds[i] = cg[i];

  // ---- phase 1: y[sh][col] = sum_p K[p][sh*3+s] * patch[p][col], 512 cols, 16 rows
  const int col = tid;
  const float* fp; int w, rr;
  if (col < 32)       { fp = f0; w = 32;  rr = col; }
  else if (col < 128) { fp = f1; w = 96;  rr = col - 32; }
  else if (col < 288) { fp = f2; w = 160; rr = col - 128; }
  else                { fp = f3; w = 224; rr = col - 288; }
  const int ml = rr >> 5, ch = rr & 31;
  const float* src = fp + (size_t)b * NSRC * w + ml * 32 + ch;

  const int*   ip = pidx + (size_t)bv * NPATCH;            // uniform -> s_load
  const float* kb = kern + (size_t)bv * NPATCH * 48 + s;   // uniform -> s_load

  float acc[16];
  #pragma unroll
  for (int y = 0; y < 16; ++y) acc[y] = 0.f;
  #pragma unroll
  for (int pc = 0; pc < 4; ++pc) {
    float vals[8];
    #pragma unroll
    for (int p = 0; p < 8; ++p) vals[p] = src[(size_t)ip[pc*8 + p] * w];
    #pragma unroll
    for (int p = 0; p < 8; ++p) {
      const float vp = vals[p];
      #pragma unroll
      for (int y = 0; y < 16; ++y)
        acc[y] = fmaf(kb[(pc*8 + p) * 48 + y * 3], vp, acc[y]);
    }
  }
  #pragma unroll
  for (int y = 0; y < 16; ++y) y_lds[y * PITCH + col] = acc[y];

  __syncthreads();

  // ---- phase 2: wave-uniform segments, lane = (z_local, ch4)
  for (int it = tid; it < NSEG * 64; it += 512) {
    const int seg  = SEGMAP[it >> 6];     // wave-uniform
    const int lane = it & 63;
    const int pu   = seg >> 1;
    const int z    = ((seg & 1) << 3) | (lane >> 3);
    const int ch4  = lane & 7;
    switch (pu) {
      case 0: pair_body<1,1>(y_lds, cg_lds, out, z, ch4, s, bv); break;
      case 1: pair_body<1,2>(y_lds, cg_lds, out, z, ch4, s, bv); break;
      case 2: pair_body<1,3>(y_lds, cg_lds, out, z, ch4, s, bv); break;
      case 3: pair_body<2,1>(y_lds, cg_lds, out, z, ch4, s, bv); break;
      case 4: pair_body<2,2>(y_lds, cg_lds, out, z, ch4, s, bv); break;
      case 5: pair_body<2,3>(y_lds, cg_lds, out, z, ch4, s, bv); break;
      case 6: pair_body<3,1>(y_lds, cg_lds, out, z, ch4, s, bv); break;
      case 7: pair_body<3,2>(y_lds, cg_lds, out, z, ch4, s, bv); break;
      case 8: pair_body<3,3>(y_lds, cg_lds, out, z, ch4, s, bv); break;
      case 9: copyA(y_lds, out, z, ch4, s, bv); break;
      default: copyB(y_lds, out, z, ch4, s, bv); break;
    }
  }
}

extern "C" void kernel_launch(void* const* d_in, const int* in_sizes, int n_in,
                              void* d_out, int out_size, void* d_ws, size_t ws_size,
                              hipStream_t stream) {
  const float* f0   = (const float*)d_in[0];
  const float* f1   = (const float*)d_in[1];
  const float* f2   = (const float*)d_in[2];
  const float* f3   = (const float*)d_in[3];
  const float* kern = (const float*)d_in[4];
  const int*   pidx = (const int*)d_in[5];
  float* out = (float*)d_out;
  float* cg  = (float*)d_ws;

  hipLaunchKernelGGL(cg_init_kernel, dim3(9), dim3(256), 0, stream, cg);
  hipLaunchKernelGGL(sh_conv_kernel, dim3(3 * 2 * NTGT), dim3(512), 0, stream,
                     f0, f1, f2, f3, kern, pidx, cg, out);
}

// Round 4
// 593.228 us; speedup vs baseline: 3.1616x; 3.1616x over previous
//
#include <hip/hip_runtime.h>
#include <hip/hip_bf16.h>

#define NTGT 2048
#define NSRC 4096
#define NPATCH 32
#define YP 260            // Y pitch in floats (260%32=4 -> bank spread, 16B aligned)
#define NCGP 3269

using short8 = __attribute__((ext_vector_type(8))) short;
using f32x4  = __attribute__((ext_vector_type(4))) float;

// n-tile (li) -> (l, ml, w/32); li = l*l + ml
__constant__ int LI_L[16]  = {0,1,1,1,2,2,2,2,2,3,3,3,3,3,3,3};
__constant__ int LI_ML[16] = {0,0,1,2,0,1,2,3,4,0,1,2,3,4,5,6};
__constant__ int LI_WQ[16] = {1,3,3,3,5,5,5,5,5,7,7,7,7,7,7,7};
// wave -> 5 segment slots; seg = pair*3+s (0..26), 27+s = copyA, 30+s = copyB, 255 = nop
__constant__ unsigned char SEGMAP[40] = {
  24,14, 9,27,255,
  25, 0, 1, 2, 30,
  26, 3, 4,28,255,
  15,21, 5,10,255,
  16,22,31,29,255,
  17,23,32,11,255,
   6, 7,18,12,255,
   8,19,20,13,255};
__constant__ int CGB_[9] = {0,81,306,558,783,1183,1708,1960,2485};

// ---------------- CG math (device, double precision) ----------------
__device__ double factd(int n) { double r = 1.0; for (int i = 2; i <= n; ++i) r *= i; return r; }

__device__ double su2_cg(int j1, int m1, int j2, int m2, int j3, int m3) {
  if (m3 != m1 + m2) return 0.0;
  int vmin = max(max(-j1 + j2 + m3, -j1 + m1), 0);
  int vmax = min(min(j2 + j3 + m1, j3 - j1 + j2), j3 + m3);
  double cc = sqrt((2.0*j3 + 1.0) * factd(j3 + j1 - j2) * factd(j3 - j1 + j2) * factd(j1 + j2 - j3)
                   / factd(j1 + j2 + j3 + 1)
                   * factd(j3 + m3) * factd(j3 - m3)
                   / (factd(j1 - m1) * factd(j1 + m1) * factd(j2 - m2) * factd(j2 + m2)));
  double s = 0.0;
  for (int v = vmin; v <= vmax; ++v) {
    double sgn = ((v + j2 + m2) & 1) ? -1.0 : 1.0;
    s += sgn * factd(j2 + j3 + m1 - v) * factd(j1 - m1 + v)
         / (factd(v) * factd(j3 - j1 + j2 - v) * factd(j3 + m3 - v) * factd(v + j1 - j2 - m3));
  }
  return cc * s;
}

struct C2 { double re, im; };

__device__ C2 qent(int l, int r, int c) {
  double re = 0.0, im = 0.0;
  const double is2 = 0.70710678118654752440;
  int m = r - l;
  if (m < 0) {
    if (c == l - m) re = is2;
    else if (c == l + m) im = -is2;
  } else if (m == 0) {
    if (c == l) re = 1.0;
  } else {
    double sgn = (m & 1) ? -1.0 : 1.0;
    if (c == l + m) re = sgn * is2;
    else if (c == l - m) im = sgn * is2;
  }
  const double pr[4] = {1.0, 0.0, -1.0, 0.0};
  const double pi[4] = {0.0, -1.0, 0.0, 1.0};
  double a = pr[l & 3], bb = pi[l & 3];
  C2 o; o.re = re * a - im * bb; o.im = re * bb + im * a; return o;
}

// layout: cg[CGB_[pair] + z_glob*(nj*nl) + mj*nl + ml], pair = (j-1)*3+(l-1)
__global__ void cg_init_kernel(float* __restrict__ cg) {
  const int p = blockIdx.x;
  const int j = p / 3 + 1, l = p % 3 + 1;
  const int Jmin = abs(j - l), Jmax = min(j + l, 3);
  const int nj = 2*j + 1, nl = 2*l + 1, njnl = nj * nl;
  __shared__ double tab[4][49];
  for (int q = threadIdx.x; q < (Jmax - Jmin + 1) * njnl; q += blockDim.x) {
    int Ji = q / njnl, ik = q % njnl;
    int J = Jmin + Ji;
    int i = ik / nl, k = ik % nl;
    int m = (i - j) + (k - l) + J;
    tab[Ji][ik] = (m >= 0 && m <= 2*J) ? su2_cg(j, i - j, l, k - l, J, m - J) : 0.0;
  }
  __syncthreads();
  const int R = (Jmax + 1) * (Jmax + 1) - Jmin * Jmin;
  const int base = CGB_[p];
  for (int e = threadIdx.x; e < R * njnl; e += blockDim.x) {
    int z = e / njnl, r = e % njnl;
    int mj = r / nl, ml = r % nl;
    int J = Jmin, zw = z;
    while (zw >= 2*J + 1) { zw -= 2*J + 1; ++J; }
    double acc = 0.0;
    for (int i = 0; i < nj; ++i)
      for (int k = 0; k < nl; ++k) {
        int m = (i - j) + (k - l) + J;
        if (m < 0 || m > 2*J) continue;
        double s2 = tab[J - Jmin][i * nl + k];
        if (s2 == 0.0) continue;
        C2 qa = qent(j, i, mj), qb = qent(l, k, ml), qc = qent(J, m, zw);
        double r1 = qa.re * qb.re - qa.im * qb.im;
        double i1 = qa.re * qb.im + qa.im * qb.re;
        acc += (r1 * qc.re + i1 * qc.im) * s2;
      }
    cg[base + e] = (float)acc;
  }
}

// ---------------- compile-time tables ----------------
__device__ constexpr int OBc(int J)  { return J==0 ? 0 : J==1 ? 1572864 : J==2 ? 12189696 : 33816576; }
__device__ constexpr int WWc(int J)  { return J==0 ? 384 : J==1 ? 864 : J==2 ? 1056 : 960; }
__device__ constexpr int NJWc(int J) { return (2*J+1) * WWc(J); }
__device__ constexpr int COLc(int j, int l, int J) {
  return (j==1&&l==1) ? (J==0?1:2)
       : (j==1&&l==2) ? (J==1?4:J==2?5:4)
       : (j==1&&l==3) ? (J==2?8:7)
       : (j==2&&l==1) ? (J==1?3:J==2?3:2)
       : (j==2&&l==2) ? (J==0?2:J==1?5:J==2?6:5)
       : (j==2&&l==3) ? (J==1?7:J==2?9:8)
       : (j==3&&l==1) ? (J==2?4:3)
       : (j==3&&l==2) ? (J==1?6:J==2?7:6)
       :                (J==0?3:J==1?8:J==2?10:9);
}
__device__ constexpr int CGBc(int j, int l) {
  return (j==1&&l==1)?0 : (j==1&&l==2)?81 : (j==1&&l==3)?306
       : (j==2&&l==1)?558 : (j==2&&l==2)?783 : (j==2&&l==3)?1183
       : (j==3&&l==1)?1708 : (j==3&&l==2)?1960 : 2485;
}

// ---------------- bf16 pack helpers ----------------
__device__ __forceinline__ unsigned bfb(float x) {
  union { __hip_bfloat16 h; unsigned short u; } c;
  c.h = __float2bfloat16(x);
  return (unsigned)c.u;
}
__device__ __forceinline__ short8 pack8(const float* v) {
  union { unsigned u[4]; short8 s; } o;
  #pragma unroll
  for (int d = 0; d < 4; ++d) o.u[d] = bfb(v[2*d]) | (bfb(v[2*d+1]) << 16);
  return o.s;
}

// ---------------- phase-2 bodies ----------------
template<int JT, int LT>
__device__ __forceinline__ void pair_body(const float* __restrict__ y_lds,
                                          const float* __restrict__ cg_lds,
                                          float* __restrict__ out,
                                          int z, int ch4, int s, int bv, int half) {
  constexpr int nj = 2*JT + 1, nl = 2*LT + 1, njnl = nj * nl;
  constexpr int Jmin = (JT > LT) ? (JT - LT) : (LT - JT);
  constexpr int Jmax = (JT + LT < 3) ? (JT + LT) : 3;
  constexpr int R = (Jmax + 1) * (Jmax + 1) - Jmin * Jmin;
  if (z >= R) return;
  const float* cgp = cg_lds + CGBc(JT, LT) + z * njnl;
  const float* yb  = y_lds + ch4 * 4;
  float a0 = 0.f, a1 = 0.f, a2 = 0.f, a3 = 0.f;
  #pragma unroll
  for (int e = 0; e < njnl; ++e) {
    const int mj = e / nl, ml = e % nl;   // compile-time after unroll
    const float4 yq = *(const float4*)(yb + ((JT*JT + mj)*3 + s) * YP + (LT*LT + ml) * 16);
    const float c = cgp[e];
    a0 = fmaf(c, yq.x, a0); a1 = fmaf(c, yq.y, a1);
    a2 = fmaf(c, yq.z, a2); a3 = fmaf(c, yq.w, a3);
  }
  int zz = z;
  #pragma unroll
  for (int J = Jmin; J <= Jmax; ++J) {
    if (zz < 2*J + 1) {
      const size_t addr = (size_t)OBc(J) + (size_t)bv * NJWc(J) + (size_t)zz * WWc(J)
                        + COLc(JT, LT, J) * 96 + s * 32 + half * 16 + ch4 * 4;
      float4 o; o.x = a0; o.y = a1; o.z = a2; o.w = a3;
      *(float4*)&out[addr] = o;
      return;
    }
    zz -= 2*J + 1;
  }
}

__device__ __forceinline__ void copyA(const float* __restrict__ y_lds, float* __restrict__ out,
                                      int z, int ch4, int s, int bv, int half) {
  const float4 yq = *(const float4*)(y_lds + (z*3 + s) * YP + ch4 * 4);
  #pragma unroll
  for (int j = 0; j < 4; ++j) {
    if (z >= j*j && z < (j+1)*(j+1)) {
      const size_t addr = (size_t)OBc(j) + (size_t)bv * NJWc(j) + (size_t)(z - j*j) * WWc(j)
                        + s * 32 + half * 16 + ch4 * 4;
      *(float4*)&out[addr] = yq;
    }
  }
}

__device__ __forceinline__ void copyB(const float* __restrict__ y_lds, float* __restrict__ out,
                                      int z, int ch4, int s, int bv, int half) {
  if (z >= 15) return;
  #pragma unroll
  for (int l = 1; l <= 3; ++l) {
    if (z >= l*l - 1 && z < l*l + 2*l) {
      const int ml = z - (l*l - 1);
      const float4 yq = *(const float4*)(y_lds + s * YP + (l*l + ml) * 16 + ch4 * 4);
      const size_t addr = (size_t)OBc(l) + (size_t)bv * NJWc(l) + (size_t)ml * WWc(l)
                        + 96 + s * 32 + half * 16 + ch4 * 4;
      *(float4*)&out[addr] = yq;
    }
  }
}

// ---------------- main fused kernel: one block per (bv, ch-half) ----------------
__global__ __launch_bounds__(512, 4) void sh_conv_kernel(
    const float* __restrict__ f0, const float* __restrict__ f1,
    const float* __restrict__ f2, const float* __restrict__ f3,
    const float* __restrict__ kern, const int* __restrict__ pidx,
    const float* __restrict__ cg, float* __restrict__ out) {
  __shared__ float y_lds[48 * YP];   // 48 x 260 f32 = 49.9 KB
  __shared__ float cg_lds[NCGP];     // 13.1 KB
  const int tid  = threadIdx.x;
  const int lane = tid & 63, wid = tid >> 6;
  const int g = lane >> 4, lr = lane & 15;
  const int bv = blockIdx.x >> 1, half = blockIdx.x & 1;
  const int b = bv >> 11;

  for (int i = tid; i < NCGP; i += 512) cg_lds[i] = cg[i];

  // ---- phase 1: Y[48 x 256] = W[48 x 32p] x P[32p x 256] via MFMA 16x16x32 bf16
  // patch indices: lanes 0..31 hold ip[0..31]; fragment k-rows via shfl
  const int ipv = pidx[(size_t)bv * NPATCH + (lane & 31)];
  int idx8[8];
  #pragma unroll
  for (int r = 0; r < 8; ++r) idx8[r] = __shfl(ipv, g * 8 + r);

  // A-frags: W[y][p] = kern[bv][p][y]; a[r] = W[m*16+lr][g*8+r]
  const float* kB = kern + (size_t)bv * (NPATCH * 48);
  short8 afr[3];
  #pragma unroll
  for (int m = 0; m < 3; ++m) {
    float av[8];
    #pragma unroll
    for (int r = 0; r < 8; ++r) av[r] = kB[(g*8 + r) * 48 + m*16 + lr];
    afr[m] = pack8(av);
  }

  f32x4 acc[2][3];
  #pragma unroll
  for (int t = 0; t < 2; ++t)
    #pragma unroll
    for (int m = 0; m < 3; ++m)
      acc[t][m] = f32x4{0.f, 0.f, 0.f, 0.f};

  #pragma unroll
  for (int t = 0; t < 2; ++t) {
    const int li = wid * 2 + t;            // wave-uniform n-tile
    const int l = LI_L[li], mlv = LI_ML[li], wq = LI_WQ[li];
    const float* fp = (l == 0) ? f0 : (l == 1) ? f1 : (l == 2) ? f2 : f3;
    const float* base = fp + ((size_t)b * NSRC) * (wq * 32) + mlv * 32 + half * 16 + lr;
    float bvv[8];
    #pragma unroll
    for (int r = 0; r < 8; ++r) bvv[r] = base[(idx8[r] * wq) << 5];
    const short8 bfr = pack8(bvv);
    #pragma unroll
    for (int m = 0; m < 3; ++m)
      acc[t][m] = __builtin_amdgcn_mfma_f32_16x16x32_bf16(afr[m], bfr, acc[t][m], 0, 0, 0);
  }

  // D: col(n)=lane&15, row(m)=g*4+q  ->  Y[m*16+g*4+q][wid*32+t*16+lr]
  #pragma unroll
  for (int t = 0; t < 2; ++t)
    #pragma unroll
    for (int m = 0; m < 3; ++m)
      #pragma unroll
      for (int q = 0; q < 4; ++q)
        y_lds[(m*16 + g*4 + q) * YP + wid*32 + t*16 + lr] = acc[t][m][q];

  __syncthreads();

  // ---- phase 2: CG contraction, wave-uniform statically-scheduled segments
  const int z = lane >> 2, ch4 = lane & 3;
  #pragma unroll 1
  for (int slot = 0; slot < 5; ++slot) {
    const int seg = SEGMAP[wid * 5 + slot];   // wave-uniform
    if (seg >= 33) continue;
    if (seg < 27) {
      const int pr = seg / 3;
      const int s  = seg - pr * 3;
      switch (pr) {
        case 0: pair_body<1,1>(y_lds, cg_lds, out, z, ch4, s, bv, half); break;
        case 1: pair_body<1,2>(y_lds, cg_lds, out, z, ch4, s, bv, half); break;
        case 2: pair_body<1,3>(y_lds, cg_lds, out, z, ch4, s, bv, half); break;
        case 3: pair_body<2,1>(y_lds, cg_lds, out, z, ch4, s, bv, half); break;
        case 4: pair_body<2,2>(y_lds, cg_lds, out, z, ch4, s, bv, half); break;
        case 5: pair_body<2,3>(y_lds, cg_lds, out, z, ch4, s, bv, half); break;
        case 6: pair_body<3,1>(y_lds, cg_lds, out, z, ch4, s, bv, half); break;
        case 7: pair_body<3,2>(y_lds, cg_lds, out, z, ch4, s, bv, half); break;
        default: pair_body<3,3>(y_lds, cg_lds, out, z, ch4, s, bv, half); break;
      }
    } else if (seg < 30) {
      copyA(y_lds, out, z, ch4, seg - 27, bv, half);
    } else {
      copyB(y_lds, out, z, ch4, seg - 30, bv, half);
    }
  }
}

extern "C" void kernel_launch(void* const* d_in, const int* in_sizes, int n_in,
                              void* d_out, int out_size, void* d_ws, size_t ws_size,
                              hipStream_t stream) {
  const float* f0   = (const float*)d_in[0];
  const float* f1   = (const float*)d_in[1];
  const float* f2   = (const float*)d_in[2];
  const float* f3   = (const float*)d_in[3];
  const float* kern = (const float*)d_in[4];
  const int*   pidx = (const int*)d_in[5];
  float* out = (float*)d_out;
  float* cg  = (float*)d_ws;

  hipLaunchKernelGGL(cg_init_kernel, dim3(9), dim3(256), 0, stream, cg);
  hipLaunchKernelGGL(sh_conv_kernel, dim3(2 * 2 * NTGT), dim3(512), 0, stream,
                     f0, f1, f2, f3, kern, pidx, cg, out);
}

// Round 5
// 589.137 us; speedup vs baseline: 3.1836x; 1.0069x over previous
//
#include <hip/hip_runtime.h>
#include <hip/hip_bf16.h>

#define NTGT 2048
#define NSRC 4096
#define NPATCH 32
#define YP 260            // Y pitch in floats (260%32=4 -> bank spread, 16B aligned)
#define NCGP 3269

using short8 = __attribute__((ext_vector_type(8))) short;
using f32x4  = __attribute__((ext_vector_type(4))) float;

// n-tile (li) -> (l, ml, w/32); li = l*l + ml
__constant__ int LI_L[16]  = {0,1,1,1,2,2,2,2,2,3,3,3,3,3,3,3};
__constant__ int LI_ML[16] = {0,0,1,2,0,1,2,3,4,0,1,2,3,4,5,6};
__constant__ int LI_WQ[16] = {1,3,3,3,5,5,5,5,5,7,7,7,7,7,7,7};
// wave -> 5 segment slots; seg = pair*3+s (0..26), 27+s = copyA, 30+s = copyB, 255 = nop
__constant__ unsigned char SEGMAP[40] = {
  24,14, 9,27,255,
  25, 0, 1, 2, 30,
  26, 3, 4,28,255,
  15,21, 5,10,255,
  16,22,31,29,255,
  17,23,32,11,255,
   6, 7,18,12,255,
   8,19,20,13,255};
__constant__ int CGB_[9] = {0,81,306,558,783,1183,1708,1960,2485};

// ---------------- CG math (device, double precision) ----------------
__device__ double factd(int n) { double r = 1.0; for (int i = 2; i <= n; ++i) r *= i; return r; }

__device__ double su2_cg(int j1, int m1, int j2, int m2, int j3, int m3) {
  if (m3 != m1 + m2) return 0.0;
  int vmin = max(max(-j1 + j2 + m3, -j1 + m1), 0);
  int vmax = min(min(j2 + j3 + m1, j3 - j1 + j2), j3 + m3);
  double cc = sqrt((2.0*j3 + 1.0) * factd(j3 + j1 - j2) * factd(j3 - j1 + j2) * factd(j1 + j2 - j3)
                   / factd(j1 + j2 + j3 + 1)
                   * factd(j3 + m3) * factd(j3 - m3)
                   / (factd(j1 - m1) * factd(j1 + m1) * factd(j2 - m2) * factd(j2 + m2)));
  double s = 0.0;
  for (int v = vmin; v <= vmax; ++v) {
    double sgn = ((v + j2 + m2) & 1) ? -1.0 : 1.0;
    s += sgn * factd(j2 + j3 + m1 - v) * factd(j1 - m1 + v)
         / (factd(v) * factd(j3 - j1 + j2 - v) * factd(j3 + m3 - v) * factd(v + j1 - j2 - m3));
  }
  return cc * s;
}

struct C2 { double re, im; };

__device__ C2 qent(int l, int r, int c) {
  double re = 0.0, im = 0.0;
  const double is2 = 0.70710678118654752440;
  int m = r - l;
  if (m < 0) {
    if (c == l - m) re = is2;
    else if (c == l + m) im = -is2;
  } else if (m == 0) {
    if (c == l) re = 1.0;
  } else {
    double sgn = (m & 1) ? -1.0 : 1.0;
    if (c == l + m) re = sgn * is2;
    else if (c == l - m) im = sgn * is2;
  }
  const double pr[4] = {1.0, 0.0, -1.0, 0.0};
  const double pi[4] = {0.0, -1.0, 0.0, 1.0};
  double a = pr[l & 3], bb = pi[l & 3];
  C2 o; o.re = re * a - im * bb; o.im = re * bb + im * a; return o;
}

// layout: cg[CGB_[pair] + z_glob*(nj*nl) + mj*nl + ml], pair = (j-1)*3+(l-1)
__global__ void cg_init_kernel(float* __restrict__ cg) {
  const int p = blockIdx.x;
  const int j = p / 3 + 1, l = p % 3 + 1;
  const int Jmin = abs(j - l), Jmax = min(j + l, 3);
  const int nj = 2*j + 1, nl = 2*l + 1, njnl = nj * nl;
  __shared__ double tab[4][49];
  for (int q = threadIdx.x; q < (Jmax - Jmin + 1) * njnl; q += blockDim.x) {
    int Ji = q / njnl, ik = q % njnl;
    int J = Jmin + Ji;
    int i = ik / nl, k = ik % nl;
    int m = (i - j) + (k - l) + J;
    tab[Ji][ik] = (m >= 0 && m <= 2*J) ? su2_cg(j, i - j, l, k - l, J, m - J) : 0.0;
  }
  __syncthreads();
  const int R = (Jmax + 1) * (Jmax + 1) - Jmin * Jmin;
  const int base = CGB_[p];
  for (int e = threadIdx.x; e < R * njnl; e += blockDim.x) {
    int z = e / njnl, r = e % njnl;
    int mj = r / nl, ml = r % nl;
    int J = Jmin, zw = z;
    while (zw >= 2*J + 1) { zw -= 2*J + 1; ++J; }
    double acc = 0.0;
    for (int i = 0; i < nj; ++i)
      for (int k = 0; k < nl; ++k) {
        int m = (i - j) + (k - l) + J;
        if (m < 0 || m > 2*J) continue;
        double s2 = tab[J - Jmin][i * nl + k];
        if (s2 == 0.0) continue;
        C2 qa = qent(j, i, mj), qb = qent(l, k, ml), qc = qent(J, m, zw);
        double r1 = qa.re * qb.re - qa.im * qb.im;
        double i1 = qa.re * qb.im + qa.im * qb.re;
        acc += (r1 * qc.re + i1 * qc.im) * s2;
      }
    cg[base + e] = (float)acc;
  }
}

// ---------------- compile-time tables ----------------
__device__ constexpr int OBc(int J)  { return J==0 ? 0 : J==1 ? 1572864 : J==2 ? 12189696 : 33816576; }
__device__ constexpr int WWc(int J)  { return J==0 ? 384 : J==1 ? 864 : J==2 ? 1056 : 960; }
__device__ constexpr int NJWc(int J) { return (2*J+1) * WWc(J); }
__device__ constexpr int COLc(int j, int l, int J) {
  return (j==1&&l==1) ? (J==0?1:2)
       : (j==1&&l==2) ? (J==1?4:J==2?5:4)
       : (j==1&&l==3) ? (J==2?8:7)
       : (j==2&&l==1) ? (J==1?3:J==2?3:2)
       : (j==2&&l==2) ? (J==0?2:J==1?5:J==2?6:5)
       : (j==2&&l==3) ? (J==1?7:J==2?9:8)
       : (j==3&&l==1) ? (J==2?4:3)
       : (j==3&&l==2) ? (J==1?6:J==2?7:6)
       :                (J==0?3:J==1?8:J==2?10:9);
}
__device__ constexpr int CGBc(int j, int l) {
  return (j==1&&l==1)?0 : (j==1&&l==2)?81 : (j==1&&l==3)?306
       : (j==2&&l==1)?558 : (j==2&&l==2)?783 : (j==2&&l==3)?1183
       : (j==3&&l==1)?1708 : (j==3&&l==2)?1960 : 2485;
}

// bf16 bits of x (RNE), in low 16 of an unsigned — no address-taken temps anywhere
__device__ __forceinline__ unsigned bfb(float x) {
  union { __hip_bfloat16 h; unsigned short u; } c;
  c.h = __float2bfloat16(x);
  return (unsigned)c.u;
}

// ---------------- phase-2 bodies (unchanged from r4) ----------------
template<int JT, int LT>
__device__ __forceinline__ void pair_body(const float* __restrict__ y_lds,
                                          const float* __restrict__ cg_lds,
                                          float* __restrict__ out,
                                          int z, int ch4, int s, int bv, int half) {
  constexpr int nj = 2*JT + 1, nl = 2*LT + 1, njnl = nj * nl;
  constexpr int Jmin = (JT > LT) ? (JT - LT) : (LT - JT);
  constexpr int Jmax = (JT + LT < 3) ? (JT + LT) : 3;
  constexpr int R = (Jmax + 1) * (Jmax + 1) - Jmin * Jmin;
  if (z >= R) return;
  const float* cgp = cg_lds + CGBc(JT, LT) + z * njnl;
  const float* yb  = y_lds + ch4 * 4;
  float a0 = 0.f, a1 = 0.f, a2 = 0.f, a3 = 0.f;
  #pragma unroll
  for (int e = 0; e < njnl; ++e) {
    const int mj = e / nl, ml = e % nl;   // compile-time after unroll
    const float4 yq = *(const float4*)(yb + ((JT*JT + mj)*3 + s) * YP + (LT*LT + ml) * 16);
    const float c = cgp[e];
    a0 = fmaf(c, yq.x, a0); a1 = fmaf(c, yq.y, a1);
    a2 = fmaf(c, yq.z, a2); a3 = fmaf(c, yq.w, a3);
  }
  int zz = z;
  #pragma unroll
  for (int J = Jmin; J <= Jmax; ++J) {
    if (zz < 2*J + 1) {
      const size_t addr = (size_t)OBc(J) + (size_t)bv * NJWc(J) + (size_t)zz * WWc(J)
                        + COLc(JT, LT, J) * 96 + s * 32 + half * 16 + ch4 * 4;
      float4 o; o.x = a0; o.y = a1; o.z = a2; o.w = a3;
      *(float4*)&out[addr] = o;
      return;
    }
    zz -= 2*J + 1;
  }
}

__device__ __forceinline__ void copyA(const float* __restrict__ y_lds, float* __restrict__ out,
                                      int z, int ch4, int s, int bv, int half) {
  const float4 yq = *(const float4*)(y_lds + (z*3 + s) * YP + ch4 * 4);
  #pragma unroll
  for (int j = 0; j < 4; ++j) {
    if (z >= j*j && z < (j+1)*(j+1)) {
      const size_t addr = (size_t)OBc(j) + (size_t)bv * NJWc(j) + (size_t)(z - j*j) * WWc(j)
                        + s * 32 + half * 16 + ch4 * 4;
      *(float4*)&out[addr] = yq;
    }
  }
}

__device__ __forceinline__ void copyB(const float* __restrict__ y_lds, float* __restrict__ out,
                                      int z, int ch4, int s, int bv, int half) {
  if (z >= 15) return;
  #pragma unroll
  for (int l = 1; l <= 3; ++l) {
    if (z >= l*l - 1 && z < l*l + 2*l) {
      const int ml = z - (l*l - 1);
      const float4 yq = *(const float4*)(y_lds + s * YP + (l*l + ml) * 16 + ch4 * 4);
      const size_t addr = (size_t)OBc(l) + (size_t)bv * NJWc(l) + (size_t)ml * WWc(l)
                        + 96 + s * 32 + half * 16 + ch4 * 4;
      *(float4*)&out[addr] = yq;
    }
  }
}

// ---------------- main fused kernel: one block per (bv, ch-half) ----------------
__global__ __launch_bounds__(512, 4) void sh_conv_kernel(
    const float* __restrict__ f0, const float* __restrict__ f1,
    const float* __restrict__ f2, const float* __restrict__ f3,
    const float* __restrict__ kern, const int* __restrict__ pidx,
    const float* __restrict__ cg, float* __restrict__ out) {
  __shared__ float y_lds[48 * YP];   // 48 x 260 f32 = 49.9 KB
  __shared__ float cg_lds[NCGP];     // 13.1 KB
  const int tid  = threadIdx.x;
  const int lane = tid & 63, wid = tid >> 6;
  const int g = lane >> 4, lr = lane & 15;
  // XCD-cohort decode: both halves of one bv land on the same XCD (bid mod 8 equal)
  const int xcd  = blockIdx.x & 7;
  const int q    = blockIdx.x >> 3;
  const int half = q & 1;
  const int bv   = ((q >> 1) << 3) | xcd;   // 0..4095, each (bv,half) exactly once
  const int b    = bv >> 11;

  for (int i = tid; i < NCGP; i += 512) cg_lds[i] = cg[i];

  // ---- phase 1: Y[48 x 256] = W[48 x 32p] x P[32p x 256] via MFMA 16x16x32 bf16
  // patch indices: lanes 0..31 hold ip[0..31]; fragment k-rows via shfl
  const int ipv = pidx[(size_t)bv * NPATCH + (lane & 31)];
  int idx8[8];
  #pragma unroll
  for (int r = 0; r < 8; ++r) idx8[r] = __shfl(ipv, g * 8 + r);

  // A-frags: W[y][p] = kern[bv][p][y]; a[r] = W[m*16+lr][g*8+r]
  // register-only packing: constant-index vector element inserts (no unions/arrays)
  const float* kB = kern + (size_t)bv * (NPATCH * 48);
  short8 afr[3];
  #pragma unroll
  for (int m = 0; m < 3; ++m) {
    short8 af;
    #pragma unroll
    for (int r = 0; r < 8; ++r)
      af[r] = (short)bfb(kB[(g*8 + r) * 48 + m*16 + lr]);
    afr[m] = af;
  }

  f32x4 acc[2][3];
  #pragma unroll
  for (int t = 0; t < 2; ++t)
    #pragma unroll
    for (int m = 0; m < 3; ++m)
      acc[t][m] = f32x4{0.f, 0.f, 0.f, 0.f};

  #pragma unroll
  for (int t = 0; t < 2; ++t) {
    const int li = wid * 2 + t;            // wave-uniform n-tile
    const int l = LI_L[li], mlv = LI_ML[li], wq = LI_WQ[li];
    const float* fp = (l == 0) ? f0 : (l == 1) ? f1 : (l == 2) ? f2 : f3;
    const float* base = fp + ((size_t)b * NSRC) * (wq * 32) + mlv * 32 + half * 16 + lr;
    short8 bfr;
    #pragma unroll
    for (int r = 0; r < 8; ++r)
      bfr[r] = (short)bfb(base[(idx8[r] * wq) << 5]);
    #pragma unroll
    for (int m = 0; m < 3; ++m)
      acc[t][m] = __builtin_amdgcn_mfma_f32_16x16x32_bf16(afr[m], bfr, acc[t][m], 0, 0, 0);
  }

  // D: col(n)=lane&15, row(m)=g*4+q  ->  Y[m*16+g*4+q][wid*32+t*16+lr]
  #pragma unroll
  for (int t = 0; t < 2; ++t)
    #pragma unroll
    for (int m = 0; m < 3; ++m)
      #pragma unroll
      for (int qq = 0; qq < 4; ++qq)
        y_lds[(m*16 + g*4 + qq) * YP + wid*32 + t*16 + lr] = acc[t][m][qq];

  __syncthreads();

  // ---- phase 2: CG contraction, wave-uniform statically-scheduled segments
  const int z = lane >> 2, ch4 = lane & 3;
  #pragma unroll 1
  for (int slot = 0; slot < 5; ++slot) {
    const int seg = SEGMAP[wid * 5 + slot];   // wave-uniform
    if (seg >= 33) continue;
    if (seg < 27) {
      const int pr = seg / 3;
      const int s  = seg - pr * 3;
      switch (pr) {
        case 0: pair_body<1,1>(y_lds, cg_lds, out, z, ch4, s, bv, half); break;
        case 1: pair_body<1,2>(y_lds, cg_lds, out, z, ch4, s, bv, half); break;
        case 2: pair_body<1,3>(y_lds, cg_lds, out, z, ch4, s, bv, half); break;
        case 3: pair_body<2,1>(y_lds, cg_lds, out, z, ch4, s, bv, half); break;
        case 4: pair_body<2,2>(y_lds, cg_lds, out, z, ch4, s, bv, half); break;
        case 5: pair_body<2,3>(y_lds, cg_lds, out, z, ch4, s, bv, half); break;
        case 6: pair_body<3,1>(y_lds, cg_lds, out, z, ch4, s, bv, half); break;
        case 7: pair_body<3,2>(y_lds, cg_lds, out, z, ch4, s, bv, half); break;
        default: pair_body<3,3>(y_lds, cg_lds, out, z, ch4, s, bv, half); break;
      }
    } else if (seg < 30) {
      copyA(y_lds, out, z, ch4, seg - 27, bv, half);
    } else {
      copyB(y_lds, out, z, ch4, seg - 30, bv, half);
    }
  }
}

extern "C" void kernel_launch(void* const* d_in, const int* in_sizes, int n_in,
                              void* d_out, int out_size, void* d_ws, size_t ws_size,
                              hipStream_t stream) {
  const float* f0   = (const float*)d_in[0];
  const float* f1   = (const float*)d_in[1];
  const float* f2   = (const float*)d_in[2];
  const float* f3   = (const float*)d_in[3];
  const float* kern = (const float*)d_in[4];
  const int*   pidx = (const int*)d_in[5];
  float* out = (float*)d_out;
  float* cg  = (float*)d_ws;

  hipLaunchKernelGGL(cg_init_kernel, dim3(9), dim3(256), 0, stream, cg);
  hipLaunchKernelGGL(sh_conv_kernel, dim3(2 * 2 * NTGT), dim3(512), 0, stream,
                     f0, f1, f2, f3, kern, pidx, cg, out);
}

// Round 6
// 269.616 us; speedup vs baseline: 6.9564x; 2.1851x over previous
//
#include <hip/hip_runtime.h>
#include <hip/hip_bf16.h>

#define NTGT 2048
#define NSRC 4096
#define NPATCH 32
#define NY 48
#define NCG 3436
#define NTERMS 34
#define NCOL 128
#define PITCH 132

using short8 = __attribute__((ext_vector_type(8))) short;
using f32x4  = __attribute__((ext_vector_type(4))) float;

// term tables: order matches reference out[J] concatenation order (r2-proven)
__constant__ int T_j[NTERMS]    = {0,1,2,3, 1,0,1,2,1,2,3,2,3, 2,0,1,2,3,1,2,3,1,2,3, 3,0,2,3,1,2,3,1,2,3};
__constant__ int T_l[NTERMS]    = {0,1,2,3, 0,1,1,1,2,2,2,3,3, 0,2,1,1,1,2,2,2,3,3,3, 0,3,1,1,2,2,2,3,3,3};
__constant__ int T_Jv[NTERMS]   = {0,0,0,0, 1,1,1,1,1,1,1,1,1, 2,2,2,2,2,2,2,2,2,2,2, 3,3,3,3,3,3,3,3,3,3};
__constant__ int T_cgoff[NTERMS]= {0,1,10,35, 84,93,102,129,174,219,294,399,504,
                                   651,676,701,746,821,926,1001,1126,1301,1406,1581,
                                   1826,1875,1924,2029,2176,2281,2456,2701,2848,3093};
__constant__ int T_col[NTERMS]  = {0,1,2,3, 0,1,2,3,4,5,6,7,8, 0,1,2,3,4,5,6,7,8,9,10, 0,1,2,3,4,5,6,7,8,9};
__constant__ int OUT_BASE[4] = {0, 1572864, 12189696, 33816576};
__constant__ int OUT_W[4]    = {384, 864, 1056, 960};
// n-tile pair of li's: li -> (l, ml, row-width/32)
__constant__ int LI_L[16]  = {0,1,1,1,2,2,2,2,2,3,3,3,3,3,3,3};
__constant__ int LI_ML[16] = {0,0,1,2,0,1,2,3,4,0,1,2,3,4,5,6};
__constant__ int LI_WQ[16] = {1,3,3,3,5,5,5,5,5,7,7,7,7,7,7,7};

// ---------------- CG table construction (r2 layout, fast version) ----------------
__device__ double factd(int n) { double r = 1.0; for (int i = 2; i <= n; ++i) r *= i; return r; }

__device__ double su2_cg(int j1, int m1, int j2, int m2, int j3, int m3) {
  if (m3 != m1 + m2) return 0.0;
  int vmin = max(max(-j1 + j2 + m3, -j1 + m1), 0);
  int vmax = min(min(j2 + j3 + m1, j3 - j1 + j2), j3 + m3);
  double cc = sqrt((2.0*j3 + 1.0) * factd(j3 + j1 - j2) * factd(j3 - j1 + j2) * factd(j1 + j2 - j3)
                   / factd(j1 + j2 + j3 + 1)
                   * factd(j3 + m3) * factd(j3 - m3)
                   / (factd(j1 - m1) * factd(j1 + m1) * factd(j2 - m2) * factd(j2 + m2)));
  double s = 0.0;
  for (int v = vmin; v <= vmax; ++v) {
    double sgn = ((v + j2 + m2) & 1) ? -1.0 : 1.0;
    s += sgn * factd(j2 + j3 + m1 - v) * factd(j1 - m1 + v)
         / (factd(v) * factd(j3 - j1 + j2 - v) * factd(j3 + m3 - v) * factd(v + j1 - j2 - m3));
  }
  return cc * s;
}

struct C2 { double re, im; };

__device__ C2 qent(int l, int r, int c) {
  double re = 0.0, im = 0.0;
  const double is2 = 0.70710678118654752440;
  int m = r - l;
  if (m < 0) {
    if (c == l - m) re = is2;
    else if (c == l + m) im = -is2;
  } else if (m == 0) {
    if (c == l) re = 1.0;
  } else {
    double sgn = (m & 1) ? -1.0 : 1.0;
    if (c == l + m) re = sgn * is2;
    else if (c == l - m) im = sgn * is2;
  }
  const double pr[4] = {1.0, 0.0, -1.0, 0.0};
  const double pi[4] = {0.0, -1.0, 0.0, 1.0};
  double a = pr[l & 3], bb = pi[l & 3];
  C2 o; o.re = re * a - im * bb; o.im = re * bb + im * a; return o;
}

// One block per term (r2 layout: cg[T_cgoff[t] + (mj*nl+ml)*nJ + mJ])
__global__ void cg_init_kernel(float* __restrict__ cg) {
  __shared__ double su2_tab[49];
  const int t = blockIdx.x;
  const int j = T_j[t], l = T_l[t], J = T_Jv[t], off = T_cgoff[t];
  const int nj = 2*j + 1, nl = 2*l + 1, nJ = 2*J + 1;
  const bool triv = (l == 0 || j == 0);
  if (!triv) {
    for (int ik = threadIdx.x; ik < nj * nl; ik += blockDim.x) {
      int i = ik / nl, k = ik - (ik / nl) * nl;
      int m = (i - j) + (k - l) + J;
      su2_tab[ik] = (m >= 0 && m <= 2*J) ? su2_cg(j, i - j, l, k - l, J, m - J) : 0.0;
    }
  }
  __syncthreads();
  const int n = nj * nl * nJ;
  for (int e = threadIdx.x; e < n; e += blockDim.x) {
    int a = e / (nl * nJ);
    int r = e - a * nl * nJ;
    int bb = r / nJ;
    int cc = r - bb * nJ;
    float v;
    if (j == 0 && l == 0)      v = 1.0f;
    else if (l == 0)           v = (a == cc) ? 1.0f : 0.0f;
    else if (j == 0)           v = (bb == cc) ? 1.0f : 0.0f;
    else {
      double acc = 0.0;
      for (int i = 0; i < nj; ++i) {
        for (int k = 0; k < nl; ++k) {
          int m = (i - j) + (k - l) + J;
          if (m < 0 || m > 2*J) continue;
          double s2 = su2_tab[i * nl + k];
          if (s2 == 0.0) continue;
          C2 qa = qent(j, i, a), qb = qent(l, k, bb), qc = qent(J, m, cc);
          double r1 = qa.re * qb.re - qa.im * qb.im;
          double i1 = qa.re * qb.im + qa.im * qb.re;
          acc += (r1 * qc.re + i1 * qc.im) * s2;
        }
      }
      v = (float)acc;
    }
    cg[off + e] = v;
  }
}

// bf16 bits of x (RNE)
__device__ __forceinline__ unsigned bfb(float x) {
  union { __hip_bfloat16 h; unsigned short u; } c;
  c.h = __float2bfloat16(x);
  return (unsigned)c.u;
}

// ---------------- phase-2 body: EXACT r2 code ----------------
template<int NJ>
__device__ __forceinline__ void do_term(const float* y_lds, const float* cg_lds,
                                        float* __restrict__ out,
                                        int j, int l, int cgo, size_t obase,
                                        int s, int ch4, int W) {
  const int nj = 2*j + 1, nl = 2*l + 1;
  const int rowbase = j*j*3 + s;          // row = (j*j + mj)*3 + s
  const int colbase = l*l*8 + ch4*4;
  float acc[NJ][4];
  #pragma unroll
  for (int z = 0; z < NJ; ++z) { acc[z][0]=0.f; acc[z][1]=0.f; acc[z][2]=0.f; acc[z][3]=0.f; }
  for (int ml = 0; ml < nl; ++ml) {
    for (int mj = 0; mj < nj; ++mj) {
      const float4 yq = *(const float4*)&y_lds[(rowbase + mj*3) * PITCH + colbase + ml*8];
      const float* cgp = &cg_lds[cgo + (mj * nl + ml) * NJ];
      #pragma unroll
      for (int z = 0; z < NJ; ++z) {
        const float cc = cgp[z];
        acc[z][0] = fmaf(cc, yq.x, acc[z][0]);
        acc[z][1] = fmaf(cc, yq.y, acc[z][1]);
        acc[z][2] = fmaf(cc, yq.z, acc[z][2]);
        acc[z][3] = fmaf(cc, yq.w, acc[z][3]);
      }
    }
  }
  #pragma unroll
  for (int z = 0; z < NJ; ++z) {
    float4 o; o.x = acc[z][0]; o.y = acc[z][1]; o.z = acc[z][2]; o.w = acc[z][3];
    *(float4*)&out[obase + (size_t)z * W] = o;
  }
}

// ---------------- main fused kernel: r2 geometry, MFMA phase 1 ----------------
__global__ __launch_bounds__(512, 6) void sh_conv_kernel(
    const float* __restrict__ f0, const float* __restrict__ f1,
    const float* __restrict__ f2, const float* __restrict__ f3,
    const float* __restrict__ kern, const int* __restrict__ pidx,
    const float* __restrict__ cg, float* __restrict__ out) {
  __shared__ float y_lds[NY * PITCH];   // 48*132*4 = 25.3 KB
  __shared__ float cg_lds[NCG];         // 13.7 KB
  const int tid = threadIdx.x;
  const int lane = tid & 63, wid = tid >> 6;
  const int g = lane >> 4, lr = lane & 15;
  // r2 grid mapping: 4 channel-blocks of one bv adjacent, same XCD
  const int xcd  = blockIdx.x & 7;
  const int slot = blockIdx.x >> 3;
  const int bv   = ((slot >> 2) << 3) | xcd;   // 0..4095
  const int cb   = slot & 3;                   // channel group: ch in [cb*8, cb*8+8)
  const int b    = bv >> 11;

  for (int i = tid; i < NCG; i += 512) cg_lds[i] = cg[i];

  // ---- phase 1 (MFMA): Y[48 x 128] = W[48 x 32] x P[32 x 128], K=32 in one step.
  // wave w owns n-tile w (cols w*16 .. w*16+15); m-tiles 0..2.
  const int ipv = pidx[(size_t)bv * NPATCH + (lane & 31)];
  int idx8[8];
  #pragma unroll
  for (int r = 0; r < 8; ++r) idx8[r] = __shfl(ipv, g * 8 + r);

  // A-frags: a[r] = W[m*16+lr][g*8+r] = kern[bv][g*8+r][m*16+lr]
  const float* kB = kern + (size_t)bv * (NPATCH * NY);
  short8 afr[3];
  #pragma unroll
  for (int m = 0; m < 3; ++m) {
    short8 af;
    #pragma unroll
    for (int r = 0; r < 8; ++r)
      af[r] = (short)bfb(kB[(g*8 + r) * NY + m*16 + lr]);
    afr[m] = af;
  }

  // B-frag: col = wid*16 + lr -> (li = wid*2 + (lr>>3), chl = lr&7); row k = g*8+r -> patch
  const int li  = wid * 2 + (lr >> 3);
  const int chl = lr & 7;
  const int l_  = LI_L[li], mlv = LI_ML[li], wq = LI_WQ[li];
  const float* fp = (l_ == 0) ? f0 : (l_ == 1) ? f1 : (l_ == 2) ? f2 : f3;
  const float* base = fp + ((size_t)b * NSRC) * (wq * 32) + mlv * 32 + cb * 8 + chl;
  short8 bfr;
  #pragma unroll
  for (int r = 0; r < 8; ++r)
    bfr[r] = (short)bfb(base[(size_t)(idx8[r] * wq) << 5]);

  f32x4 acc0 = {0.f,0.f,0.f,0.f}, acc1 = {0.f,0.f,0.f,0.f}, acc2 = {0.f,0.f,0.f,0.f};
  acc0 = __builtin_amdgcn_mfma_f32_16x16x32_bf16(afr[0], bfr, acc0, 0, 0, 0);
  acc1 = __builtin_amdgcn_mfma_f32_16x16x32_bf16(afr[1], bfr, acc1, 0, 0, 0);
  acc2 = __builtin_amdgcn_mfma_f32_16x16x32_bf16(afr[2], bfr, acc2, 0, 0, 0);

  // D: col(n)=lane&15, row(m)=g*4+q -> y_lds[(m*16+g*4+q)][wid*16+lr]
  #pragma unroll
  for (int q = 0; q < 4; ++q) {
    y_lds[(0*16 + g*4 + q) * PITCH + wid*16 + lr] = acc0[q];
    y_lds[(1*16 + g*4 + q) * PITCH + wid*16 + lr] = acc1[q];
    y_lds[(2*16 + g*4 + q) * PITCH + wid*16 + lr] = acc2[q];
  }

  __syncthreads();

  // ---- phase 2: EXACT r2 structure; item = (term, s, ch4), 204 items, single pass
  if (tid < NTERMS * 6) {
    const int term = tid / 6;
    const int rem  = tid - term * 6;
    const int s = rem >> 1, ch4 = rem & 1;
    const int j = T_j[term], l = T_l[term], J = T_Jv[term];
    const int cgo = T_cgoff[term];
    const int W = OUT_W[J];
    const size_t obase = (size_t)OUT_BASE[J] + (size_t)bv * (2*J + 1) * W
                       + T_col[term] * 96 + s * 32 + cb * 8 + ch4 * 4;
    switch (J) {
      case 0:  do_term<1>(y_lds, cg_lds, out, j, l, cgo, obase, s, ch4, W); break;
      case 1:  do_term<3>(y_lds, cg_lds, out, j, l, cgo, obase, s, ch4, W); break;
      case 2:  do_term<5>(y_lds, cg_lds, out, j, l, cgo, obase, s, ch4, W); break;
      default: do_term<7>(y_lds, cg_lds, out, j, l, cgo, obase, s, ch4, W); break;
    }
  }
}

extern "C" void kernel_launch(void* const* d_in, const int* in_sizes, int n_in,
                              void* d_out, int out_size, void* d_ws, size_t ws_size,
                              hipStream_t stream) {
  const float* f0   = (const float*)d_in[0];
  const float* f1   = (const float*)d_in[1];
  const float* f2   = (const float*)d_in[2];
  const float* f3   = (const float*)d_in[3];
  const float* kern = (const float*)d_in[4];
  const int*   pidx = (const int*)d_in[5];
  float* out = (float*)d_out;
  float* cg  = (float*)d_ws;

  hipLaunchKernelGGL(cg_init_kernel, dim3(NTERMS), dim3(256), 0, stream, cg);
  hipLaunchKernelGGL(sh_conv_kernel, dim3(4 * 2 * NTGT), dim3(512), 0, stream,
                     f0, f1, f2, f3, kern, pidx, cg, out);
}

// Round 7
// 199.906 us; speedup vs baseline: 9.3823x; 1.3487x over previous
//
#include <hip/hip_runtime.h>
#include <hip/hip_bf16.h>

#define NTGT 2048
#define NSRC 4096
#define NPATCH 32
#define NY 48
#define NCG 3436
#define NTERMS 34
#define PITCH 132
#define NSLOTS 1024
#define DESC_OFF 16384   // byte offset of descriptor table in d_ws

using short8 = __attribute__((ext_vector_type(8))) short;
using f32x4  = __attribute__((ext_vector_type(4))) float;

// term tables: order matches reference out[J] concatenation order (r2-proven)
__constant__ int T_j[NTERMS]    = {0,1,2,3, 1,0,1,2,1,2,3,2,3, 2,0,1,2,3,1,2,3,1,2,3, 3,0,2,3,1,2,3,1,2,3};
__constant__ int T_l[NTERMS]    = {0,1,2,3, 0,1,1,1,2,2,2,3,3, 0,2,1,1,1,2,2,2,3,3,3, 0,3,1,1,2,2,2,3,3,3};
__constant__ int T_Jv[NTERMS]   = {0,0,0,0, 1,1,1,1,1,1,1,1,1, 2,2,2,2,2,2,2,2,2,2,2, 3,3,3,3,3,3,3,3,3,3};
__constant__ int T_cgoff[NTERMS]= {0,1,10,35, 84,93,102,129,174,219,294,399,504,
                                   651,676,701,746,821,926,1001,1126,1301,1406,1581,
                                   1826,1875,1924,2029,2176,2281,2456,2701,2848,3093};
__constant__ int T_col[NTERMS]  = {0,1,2,3, 0,1,2,3,4,5,6,7,8, 0,1,2,3,4,5,6,7,8,9,10, 0,1,2,3,4,5,6,7,8,9};
__constant__ int OUT_BASE[4] = {0, 1572864, 12189696, 33816576};
__constant__ int OUT_W[4]    = {384, 864, 1056, 960};
__constant__ int NJW_C[4]    = {384, 2592, 5280, 6720};   // (2J+1)*W
// n-tile pair of li's: li -> (l, ml, row-width/32)
__constant__ int LI_L[16]  = {0,1,1,1,2,2,2,2,2,3,3,3,3,3,3,3};
__constant__ int LI_ML[16] = {0,0,1,2,0,1,2,3,4,0,1,2,3,4,5,6};
__constant__ int LI_WQ[16] = {1,3,3,3,5,5,5,5,5,7,7,7,7,7,7,7};
// phase-2 schedule: terms sorted by descending nj*nl (wave-uniform loop bounds)
__constant__ int SEQ_TERM[NTERMS] = {3,12,23,33, 10,20,30, 11,22,32, 2,9,19,29,
                                     17,27, 21,31, 7,16,26, 8,18,28, 1,6,15,
                                     24,13,4,0, 25,14,5};
__constant__ int SEQ_BASE[NTERMS] = {0,6,24,54, 96,114,144, 186,204,234, 276,282,300,330,
                                     372,402, 444,474, 516,534,564, 606,624,654, 696,702,720,
                                     750,792,822,840, 846,888,918};

// ---------------- CG table construction (device, double precision) ----------------
__device__ double factd(int n) { double r = 1.0; for (int i = 2; i <= n; ++i) r *= i; return r; }

__device__ double su2_cg(int j1, int m1, int j2, int m2, int j3, int m3) {
  if (m3 != m1 + m2) return 0.0;
  int vmin = max(max(-j1 + j2 + m3, -j1 + m1), 0);
  int vmax = min(min(j2 + j3 + m1, j3 - j1 + j2), j3 + m3);
  double cc = sqrt((2.0*j3 + 1.0) * factd(j3 + j1 - j2) * factd(j3 - j1 + j2) * factd(j1 + j2 - j3)
                   / factd(j1 + j2 + j3 + 1)
                   * factd(j3 + m3) * factd(j3 - m3)
                   / (factd(j1 - m1) * factd(j1 + m1) * factd(j2 - m2) * factd(j2 + m2)));
  double s = 0.0;
  for (int v = vmin; v <= vmax; ++v) {
    double sgn = ((v + j2 + m2) & 1) ? -1.0 : 1.0;
    s += sgn * factd(j2 + j3 + m1 - v) * factd(j1 - m1 + v)
         / (factd(v) * factd(j3 - j1 + j2 - v) * factd(j3 + m3 - v) * factd(v + j1 - j2 - m3));
  }
  return cc * s;
}

struct C2 { double re, im; };

__device__ C2 qent(int l, int r, int c) {
  double re = 0.0, im = 0.0;
  const double is2 = 0.70710678118654752440;
  int m = r - l;
  if (m < 0) {
    if (c == l - m) re = is2;
    else if (c == l + m) im = -is2;
  } else if (m == 0) {
    if (c == l) re = 1.0;
  } else {
    double sgn = (m & 1) ? -1.0 : 1.0;
    if (c == l + m) re = sgn * is2;
    else if (c == l - m) im = sgn * is2;
  }
  const double pr[4] = {1.0, 0.0, -1.0, 0.0};
  const double pi[4] = {0.0, -1.0, 0.0, 1.0};
  double a = pr[l & 3], bb = pi[l & 3];
  C2 o; o.re = re * a - im * bb; o.im = re * bb + im * a; return o;
}

// One block per term (r2 layout: cg[T_cgoff[t] + (mj*nl+ml)*nJ + mJ])
__global__ void cg_init_kernel(float* __restrict__ cg) {
  __shared__ double su2_tab[49];
  const int t = blockIdx.x;
  const int j = T_j[t], l = T_l[t], J = T_Jv[t], off = T_cgoff[t];
  const int nj = 2*j + 1, nl = 2*l + 1, nJ = 2*J + 1;
  const bool triv = (l == 0 || j == 0);
  if (!triv) {
    for (int ik = threadIdx.x; ik < nj * nl; ik += blockDim.x) {
      int i = ik / nl, k = ik - (ik / nl) * nl;
      int m = (i - j) + (k - l) + J;
      su2_tab[ik] = (m >= 0 && m <= 2*J) ? su2_cg(j, i - j, l, k - l, J, m - J) : 0.0;
    }
  }
  __syncthreads();
  const int n = nj * nl * nJ;
  for (int e = threadIdx.x; e < n; e += blockDim.x) {
    int a = e / (nl * nJ);
    int r = e - a * nl * nJ;
    int bb = r / nJ;
    int cc = r - bb * nJ;
    float v;
    if (j == 0 && l == 0)      v = 1.0f;
    else if (l == 0)           v = (a == cc) ? 1.0f : 0.0f;
    else if (j == 0)           v = (bb == cc) ? 1.0f : 0.0f;
    else {
      double acc = 0.0;
      for (int i = 0; i < nj; ++i) {
        for (int k = 0; k < nl; ++k) {
          int m = (i - j) + (k - l) + J;
          if (m < 0 || m > 2*J) continue;
          double s2 = su2_tab[i * nl + k];
          if (s2 == 0.0) continue;
          C2 qa = qent(j, i, a), qb = qent(l, k, bb), qc = qent(J, m, cc);
          double r1 = qa.re * qb.re - qa.im * qb.im;
          double i1 = qa.re * qb.im + qa.im * qb.re;
          acc += (r1 * qc.re + i1 * qc.im) * s2;
        }
      }
      v = (float)acc;
    }
    cg[off + e] = v;
  }
}

// ---------------- phase-2 item descriptor table ----------------
// item = (term, z, s, ch4); 936 real slots + nops to 1024.
// word0 = out offset (bv/cb-independent part)
// word1 = ybase(12b) | cgz(12b)<<12 | j<<24 | l<<26 | J<<28  (J=7 -> nop)
__global__ void desc_init_kernel(uint2* __restrict__ desc) {
  const int t = blockIdx.x;
  const int term = SEQ_TERM[t];
  const int j = T_j[term], l = T_l[term], J = T_Jv[term];
  const int n = (2*J + 1) * 6;
  const int base = SEQ_BASE[t];
  for (int i = threadIdx.x; i < n; i += blockDim.x) {
    const int z = i / 6, r = i - (i / 6) * 6;
    const int s = r >> 1, ch4 = r & 1;
    uint2 d;
    d.x = (unsigned)(OUT_BASE[J] + T_col[term] * 96 + s * 32 + ch4 * 4 + z * OUT_W[J]);
    d.y = (unsigned)((j*j*3 + s) * PITCH + l*l*8 + ch4*4)
        | ((unsigned)(T_cgoff[term] + z) << 12)
        | ((unsigned)j << 24) | ((unsigned)l << 26) | ((unsigned)J << 28);
    desc[base + i] = d;
  }
  if (t == NTERMS - 1) {
    for (int s2 = 936 + threadIdx.x; s2 < NSLOTS; s2 += blockDim.x)
      desc[s2] = make_uint2(0u, 0x70000000u);   // J=7 sentinel
  }
}

// bf16 bits of x (RNE)
__device__ __forceinline__ unsigned bfb(float x) {
  union { __hip_bfloat16 h; unsigned short u; } c;
  c.h = __float2bfloat16(x);
  return (unsigned)c.u;
}

// ---------------- main fused kernel: r6 geometry + phase-2 item scheduler ----------------
__global__ __launch_bounds__(512, 6) void sh_conv_kernel(
    const float* __restrict__ f0, const float* __restrict__ f1,
    const float* __restrict__ f2, const float* __restrict__ f3,
    const float* __restrict__ kern, const int* __restrict__ pidx,
    const float* __restrict__ cg, const uint2* __restrict__ desc,
    float* __restrict__ out) {
  __shared__ float y_lds[NY * PITCH];   // 25.3 KB
  __shared__ float cg_lds[NCG];         // 13.7 KB
  const int tid = threadIdx.x;
  const int lane = tid & 63, wid = tid >> 6;
  const int g = lane >> 4, lr = lane & 15;
  // r2/r6 grid mapping: 4 channel-blocks of one bv adjacent, same XCD
  const int xcd  = blockIdx.x & 7;
  const int slot = blockIdx.x >> 3;
  const int bv   = ((slot >> 2) << 3) | xcd;   // 0..4095
  const int cb   = slot & 3;                   // channel group: ch in [cb*8, cb*8+8)
  const int b    = bv >> 11;

  for (int i = tid; i < NCG; i += 512) cg_lds[i] = cg[i];

  // ---- phase 1 (MFMA, unchanged from r6): Y[48 x 128] = W[48 x 32] x P[32 x 128]
  const int ipv = pidx[(size_t)bv * NPATCH + (lane & 31)];
  int idx8[8];
  #pragma unroll
  for (int r = 0; r < 8; ++r) idx8[r] = __shfl(ipv, g * 8 + r);

  const float* kB = kern + (size_t)bv * (NPATCH * NY);
  short8 afr[3];
  #pragma unroll
  for (int m = 0; m < 3; ++m) {
    short8 af;
    #pragma unroll
    for (int r = 0; r < 8; ++r)
      af[r] = (short)bfb(kB[(g*8 + r) * NY + m*16 + lr]);
    afr[m] = af;
  }

  const int li  = wid * 2 + (lr >> 3);
  const int chl = lr & 7;
  const int l_  = LI_L[li], mlv = LI_ML[li], wq = LI_WQ[li];
  const float* fp = (l_ == 0) ? f0 : (l_ == 1) ? f1 : (l_ == 2) ? f2 : f3;
  const float* base = fp + ((size_t)b * NSRC) * (wq * 32) + mlv * 32 + cb * 8 + chl;
  short8 bfr;
  #pragma unroll
  for (int r = 0; r < 8; ++r)
    bfr[r] = (short)bfb(base[(size_t)(idx8[r] * wq) << 5]);

  f32x4 acc0 = {0.f,0.f,0.f,0.f}, acc1 = {0.f,0.f,0.f,0.f}, acc2 = {0.f,0.f,0.f,0.f};
  acc0 = __builtin_amdgcn_mfma_f32_16x16x32_bf16(afr[0], bfr, acc0, 0, 0, 0);
  acc1 = __builtin_amdgcn_mfma_f32_16x16x32_bf16(afr[1], bfr, acc1, 0, 0, 0);
  acc2 = __builtin_amdgcn_mfma_f32_16x16x32_bf16(afr[2], bfr, acc2, 0, 0, 0);

  #pragma unroll
  for (int q = 0; q < 4; ++q) {
    y_lds[(0*16 + g*4 + q) * PITCH + wid*16 + lr] = acc0[q];
    y_lds[(1*16 + g*4 + q) * PITCH + wid*16 + lr] = acc1[q];
    y_lds[(2*16 + g*4 + q) * PITCH + wid*16 + lr] = acc2[q];
  }

  __syncthreads();

  // ---- phase 2: 936 items (term,z,s,ch4) over all 512 threads, 2 rounds.
  // Sorted by (j,l) cost -> wave-uniform loop bounds. Store set identical to r6.
  #pragma unroll 1
  for (int rnd = 0; rnd < 2; ++rnd) {
    const uint2 d = desc[rnd * 512 + tid];
    const unsigned w1 = d.y;
    const int J = (w1 >> 28) & 7;
    if (J > 3) continue;
    const int j = (w1 >> 24) & 3, l = (w1 >> 26) & 3;
    const int nj = 2*j + 1, nl = 2*l + 1, nJ = 2*J + 1;
    const float* yb  = y_lds + (w1 & 0xFFF);
    const float* cgp = cg_lds + ((w1 >> 12) & 0xFFF);
    float a0 = 0.f, a1 = 0.f, a2 = 0.f, a3 = 0.f;
    int cgi = 0;
    #pragma unroll 1
    for (int mj = 0; mj < nj; ++mj) {
      const float* yr = yb + mj * 3 * PITCH;
      #pragma unroll 1
      for (int ml = 0; ml < nl; ++ml) {
        const float4 yq = *(const float4*)(yr + ml * 8);
        const float c = cgp[cgi]; cgi += nJ;
        a0 = fmaf(c, yq.x, a0); a1 = fmaf(c, yq.y, a1);
        a2 = fmaf(c, yq.z, a2); a3 = fmaf(c, yq.w, a3);
      }
    }
    const size_t addr = (size_t)d.x + (size_t)bv * NJW_C[J] + cb * 8;
    float4 o; o.x = a0; o.y = a1; o.z = a2; o.w = a3;
    *(float4*)&out[addr] = o;
  }
}

extern "C" void kernel_launch(void* const* d_in, const int* in_sizes, int n_in,
                              void* d_out, int out_size, void* d_ws, size_t ws_size,
                              hipStream_t stream) {
  const float* f0   = (const float*)d_in[0];
  const float* f1   = (const float*)d_in[1];
  const float* f2   = (const float*)d_in[2];
  const float* f3   = (const float*)d_in[3];
  const float* kern = (const float*)d_in[4];
  const int*   pidx = (const int*)d_in[5];
  float* out  = (float*)d_out;
  float* cg   = (float*)d_ws;
  uint2* desc = (uint2*)((char*)d_ws + DESC_OFF);

  hipLaunchKernelGGL(cg_init_kernel, dim3(NTERMS), dim3(256), 0, stream, cg);
  hipLaunchKernelGGL(desc_init_kernel, dim3(NTERMS), dim3(64), 0, stream, desc);
  hipLaunchKernelGGL(sh_conv_kernel, dim3(4 * 2 * NTGT), dim3(512), 0, stream,
                     f0, f1, f2, f3, kern, pidx, cg, desc, out);
}